// Round 14
// baseline (360.987 us; speedup 1.0000x reference)
//
#include <hip/hip_runtime.h>

#define NUM_USER 60000
#define NUM_ITEM 40000
#define NN 100000
#define NE 500000
#define DIM 64
#define KF 4
#define SCAN_CHUNK 512
#define NBLK_SCAN ((NN + 1 + SCAN_CHUNK - 1) / SCAN_CHUNK)
// padded slot-count upper bounds (each node rounds up to multiple of 4)
#define NEPU_MAX (NE + 3 * NUM_USER)   // 680000 user-side slots max
#define NEPI_MAX (NE + 3 * NUM_ITEM)   // 620000 item-side slots max
#define NSLOT_MAX (NEPU_MAX + NEPI_MAX)
#define MAXU_SLOTS 44                  // register-cached user path handles <=44 slots
#define NB_U4 (NUM_USER * DIM / 4 / 256)   // 3750 user-init blocks (float4/thread)
#define NB_I (NUM_ITEM / 16)               // 2500 item-init blocks (16 nodes/block)
#define NB_SETUP (NB_U4 + NB_I)            // 6250
#define EPB (NE / NB_SETUP)                // 80 edges counted per setup block
#define NPART 8                            // count partitions (~XCD count)

// sum within each 16-lane group (butterfly: all lanes get result)
__device__ __forceinline__ float red16(float v) {
    v += __shfl_xor(v, 1);
    v += __shfl_xor(v, 2);
    v += __shfl_xor(v, 4);
    v += __shfl_xor(v, 8);
    return v;
}

__device__ __forceinline__ float b2f(unsigned short u) {
    return __uint_as_float(((unsigned)u) << 16);
}
__device__ __forceinline__ unsigned short f2b(float x) {
    unsigned u = __float_as_uint(x);
    u = (u + 0x7fffu + ((u >> 16) & 1u)) >> 16;   // RNE
    return (unsigned short)u;
}
// combined item word: high16 = T (bf16 bits), low16 = ego (bf16 bits)
__device__ __forceinline__ float cvt_lo(unsigned c) { return __uint_as_float(c << 16); }
__device__ __forceinline__ float cvt_hi(unsigned c) { return __uint_as_float(c & 0xffff0000u); }
// pack hi16 halves of two combined words: lo16(out)=hi16(c0), hi16(out)=hi16(c1)
__device__ __forceinline__ unsigned packhi(unsigned c0, unsigned c1) {
#if defined(__has_builtin) && __has_builtin(__builtin_amdgcn_perm)
    return __builtin_amdgcn_perm(c1, c0, 0x07060302u);
#else
    return (c0 >> 16) | (c1 & 0xffff0000u);
#endif
}
// mixed-butterfly level: lane keeps the value whose slot-bit matches its lane bit
__device__ __forceinline__ float mixv(float x, float y, bool b, int m) {
    return (b ? y : x) + __shfl_xor(b ? x : y, m);
}

__device__ __forceinline__ float4 softmax4(float4 s) {
    float m = fmaxf(fmaxf(s.x, s.y), fmaxf(s.z, s.w));
    float e0 = __expf(s.x - m), e1 = __expf(s.y - m);
    float e2 = __expf(s.z - m), e3 = __expf(s.w - m);
    float inv = 1.0f / (e0 + e1 + e2 + e3);
    return make_float4(e0 * inv, e1 * inv, e2 * inv, e3 * inv);
}

// Per-user-slot 32B record (ONE cache line): rec4[2j]={jit, n, 1/n, 0},
// rec4[2j+1]={w0,w1,w2,w3}. Dummy slots all-zero from bulk memset
// (n=0 -> update skipped; w=0 -> conv contribution zero).
#define RW(j, k) recf[8 * (j) + 4 + (k)]

// Fused per-slot S/weight update (single record: every access to a user slot
// is by its owning lane, read-before-write in program order).
// softmax(S_old) reconstructed as w*(1/n). snew = w*rn + dot.
// last: S4f <- snew (final output); else w' = n*softmax_k(snew) -> record
// (+ wi item-order scatter only when writeWi; it=1's wi is never consumed).
__device__ __forceinline__ void fused_upd(int jj, int k, float dot, bool wr,
        int4* __restrict__ rec4, float* __restrict__ S4f,
        float* __restrict__ wiW, int last, int writeWi) {
    float* recf = (float*)rec4;
    float w = RW(jj, k);
    int4 h = rec4[2 * jj];
    float n = __int_as_float(h.y);
    float rn = __int_as_float(h.z);
    float snew = fmaf(w, rn, dot);
    if (last) {
        if (wr) S4f[4 * jj + k] = snew;
        return;
    }
    float m2 = fmaxf(snew, __shfl_xor(snew, 16));
    m2 = fmaxf(m2, __shfl_xor(m2, 32));
    float e2 = __expf(snew - m2);
    float s2 = e2 + __shfl_xor(e2, 16);
    s2 += __shfl_xor(s2, 32);
    if (wr && n > 0.0f) {
        float wn = n * e2 * (1.0f / s2);
        RW(jj, k) = wn;
        if (writeWi) wiW[4 * h.x + k] = wn;
    }
}

// init (vectorized 4 dims/thread) + PARTITIONED degree count: partition
// p = blockIdx&7 ~ XCD id under round-robin dispatch, so each partition's
// counter lines stay in ONE XCD's L2 (no cross-XCD atomic ping-pong; any
// other mapping is still correct, just less local). Rank packed with p.
__global__ void k_setup(const float* __restrict__ user, const float* __restrict__ item,
                        unsigned short* __restrict__ egoU, unsigned* __restrict__ cmbI,
                        float* __restrict__ allemb, const int* __restrict__ row0,
                        const int* __restrict__ col0, int* __restrict__ cnt8,
                        unsigned* __restrict__ rankR, unsigned* __restrict__ rankC) {
    int b = blockIdx.x, t = threadIdx.x;
    int ebase = b * EPB;
    unsigned ptag = (unsigned)(b & (NPART - 1));
    int* cp = cnt8 + (int)ptag * NN;
    if (t < EPB) {
        int nd = row0[ebase + t];
        rankR[ebase + t] = (unsigned)atomicAdd(&cp[nd], 1) | (ptag << 28);
    } else if (t < 2 * EPB) {
        int nd = col0[ebase + t - EPB];
        rankC[ebase + t - EPB] = (unsigned)atomicAdd(&cp[nd], 1) | (ptag << 28);
    }
    if (b < NB_U4) {
        // user: pure streaming copy, float4/thread
        int idx = (b * 256 + t) * 4;
        float4 v = *(const float4*)(user + idx);
        ushort4 e;
        e.x = f2b(v.x); e.y = f2b(v.y); e.z = f2b(v.z); e.w = f2b(v.w);
        *(ushort4*)(egoU + idx) = e;
        *(float4*)(allemb + idx) = v;
    } else {
        // item: 16 lanes/node, float4/lane; 16-dim norm = 4-lane reduce
        int bb = b - NB_U4;
        int lane = t & 63;
        int nodeI = bb * 16 + ((t >> 6) << 2) + (lane >> 4);
        int idx = nodeI * DIM + (lane & 15) * 4;
        float4 v = *(const float4*)(item + idx);
        float ss = v.x * v.x + v.y * v.y + v.z * v.z + v.w * v.w;
        ss += __shfl_xor(ss, 1);
        ss += __shfl_xor(ss, 2);
        float rinv = 1.0f / fmaxf(sqrtf(ss), 1e-12f);
        uint4 o;
        o.x = (((unsigned)f2b(tanhf(v.x * rinv))) << 16) | (unsigned)f2b(v.x);
        o.y = (((unsigned)f2b(tanhf(v.y * rinv))) << 16) | (unsigned)f2b(v.y);
        o.z = (((unsigned)f2b(tanhf(v.z * rinv))) << 16) | (unsigned)f2b(v.z);
        o.w = (((unsigned)f2b(tanhf(v.w * rinv))) << 16) | (unsigned)f2b(v.w);
        *(uint4*)(cmbI + idx) = o;
        *(float4*)(allemb + NUM_USER * DIM + idx) = v;
    }
}

// --- 3-stage exclusive scan over padded counts -> ptr[NN+1] ---
// scan1 also: sums the 8 count partitions, writes per-partition exclusive
// bases (base8) + total degree (cnt, no longer atomic-written) + dinv.
__global__ void k_scan1(const int* __restrict__ cnt8, int* __restrict__ base8,
                        int* __restrict__ cnt, float* __restrict__ dinv,
                        int* __restrict__ ptr, int* __restrict__ bsum) {
    __shared__ int sm[SCAN_CHUNK];
    int tid = threadIdx.x;
    int idx = blockIdx.x * SCAN_CHUNK + tid;
    int d = 0;
    if (idx < NN) {
#pragma unroll
        for (int p = 0; p < NPART; ++p) {
            base8[p * NN + idx] = d;
            d += cnt8[p * NN + idx];
        }
        cnt[idx] = d;
        dinv[idx] = (d > 0) ? rsqrtf((float)d) : 0.0f;
    }
    int x = (d + 3) & ~3;
    sm[tid] = x;
    __syncthreads();
    for (int off = 1; off < SCAN_CHUNK; off <<= 1) {
        int v = (tid >= off) ? sm[tid - off] : 0;
        __syncthreads();
        sm[tid] += v;
        __syncthreads();
    }
    if (idx <= NN) ptr[idx] = sm[tid] - x;
    if (tid == SCAN_CHUNK - 1) bsum[blockIdx.x] = sm[tid];
}

__global__ void k_scan2(int* __restrict__ bsum, int* __restrict__ offs) {
    __shared__ int sm[256];
    int tid = threadIdx.x;
    int x = (tid < NBLK_SCAN) ? bsum[tid] : 0;
    sm[tid] = x;
    __syncthreads();
    for (int off = 1; off < 256; off <<= 1) {
        int v = (tid >= off) ? sm[tid - off] : 0;
        __syncthreads();
        sm[tid] += v;
        __syncthreads();
    }
    if (tid < NBLK_SCAN) offs[tid] = sm[tid] - x;
}

// finalize scan; zero dummy-slot srcadj (end computable locally from cnt)
__global__ void k_scan3(int* __restrict__ ptr, const int* __restrict__ offs,
                        const int* __restrict__ cnt, int* __restrict__ srcadj) {
    int idx = blockIdx.x * blockDim.x + threadIdx.x;
    if (idx > NN) return;
    int v = ptr[idx] + offs[idx / SCAN_CHUNK];
    ptr[idx] = v;
    if (idx < NN) {
        int d = cnt[idx];
        int end = v + ((d + 3) & ~3);
        for (int j = v + d; j < end; ++j) srcadj[j] = 0;
    }
}

// fill CSR + w0, ATOMIC-FREE: j = ptr[node] + base8[p][node] + rank, with
// {p, rank} from the packed value captured in setup. Per edge: coalesced
// row/col/rank/Sin reads, L2/L3-resident ptr/dinv/base8 gathers, 3 scattered
// lines: srcadj[j1], srcadj[j0], rec[j1] (32B, one line).
__global__ void k_fillw0(const int* __restrict__ row0, const int* __restrict__ col0,
                         const unsigned* __restrict__ rankR,
                         const unsigned* __restrict__ rankC,
                         const float* __restrict__ Sin, const float* __restrict__ dinv,
                         const int* __restrict__ ptr, const int* __restrict__ base8,
                         int* __restrict__ srcadj, int4* __restrict__ rec4,
                         int* __restrict__ jpos1) {
    int e = blockIdx.x * blockDim.x + threadIdx.x;
    if (e >= NE) return;
    int r = row0[e], c = col0[e];
    int ptrU = ptr[NUM_USER];
    unsigned rr = rankR[e], rc = rankC[e];
    int j1 = ptr[r] + base8[(int)(rr >> 28) * NN + r] + (int)(rr & 0x0FFFFFFFu);
    int j0 = ptr[c] + base8[(int)(rc >> 28) * NN + c] + (int)(rc & 0x0FFFFFFFu);
    srcadj[j1] = (c - NUM_USER) << 6;
    srcadj[j0] = r << 6;
    jpos1[e] = j1;
    float n = dinv[r] * dinv[c];
    float4 s = make_float4(Sin[e], Sin[NE + e], Sin[2 * NE + e], Sin[3 * NE + e]);
    float4 p = softmax4(s);
    rec4[2 * j1] = make_int4(j0 - ptrU, __float_as_int(n),
                             __float_as_int(1.0f / n), 0);
    rec4[2 * j1 + 1] = make_int4(__float_as_int(n * p.x), __float_as_int(n * p.y),
                                 __float_as_int(n * p.z), __float_as_int(n * p.w));
}

// Scur4 (slot order) -> Sout [4][E] edge order; 4 edges/thread (int4 jpos1,
// float4 plane writes, 4 gathers in flight)
__global__ void k_sout(const float4* __restrict__ Scur4, const int* __restrict__ jpos1,
                       float* __restrict__ Sout) {
    int t4 = blockIdx.x * blockDim.x + threadIdx.x;
    if (t4 >= NE / 4) return;
    int4 jp = ((const int4*)jpos1)[t4];
    float4 s0 = Scur4[jp.x];
    float4 s1 = Scur4[jp.y];
    float4 s2 = Scur4[jp.z];
    float4 s3 = Scur4[jp.w];
    int e = t4 * 4;
    *(float4*)(Sout + e) = make_float4(s0.x, s1.x, s2.x, s3.x);
    *(float4*)(Sout + NE + e) = make_float4(s0.y, s1.y, s2.y, s3.y);
    *(float4*)(Sout + 2 * NE + e) = make_float4(s0.z, s1.z, s2.z, s3.z);
    *(float4*)(Sout + 3 * NE + e) = make_float4(s0.w, s1.w, s2.w, s3.w);
}

// ---- user conv block macros: 16 outstanding gathers per issue point ----
// (srcadj values pre-scaled by DIM; weights from the slot record stream)
#define UCONV16(JOFF, TP0) do { \
    int j = beg + (JOFF); \
    int4 sA = *(const int4*)(srcadj + j); \
    int4 sB = *(const int4*)(srcadj + j + 4); \
    int4 sC = *(const int4*)(srcadj + j + 8); \
    int4 sD = *(const int4*)(srcadj + j + 12); \
    unsigned c0 = cmbI[sA.x + lane]; \
    unsigned c1 = cmbI[sA.y + lane]; \
    unsigned c2 = cmbI[sA.z + lane]; \
    unsigned c3 = cmbI[sA.w + lane]; \
    unsigned c4 = cmbI[sB.x + lane]; \
    unsigned c5 = cmbI[sB.y + lane]; \
    unsigned c6 = cmbI[sB.z + lane]; \
    unsigned c7 = cmbI[sB.w + lane]; \
    unsigned c8 = cmbI[sC.x + lane]; \
    unsigned c9 = cmbI[sC.y + lane]; \
    unsigned c10 = cmbI[sC.z + lane]; \
    unsigned c11 = cmbI[sC.w + lane]; \
    unsigned c12 = cmbI[sD.x + lane]; \
    unsigned c13 = cmbI[sD.y + lane]; \
    unsigned c14 = cmbI[sD.z + lane]; \
    unsigned c15 = cmbI[sD.w + lane]; \
    a0 = fmaf(RW(j + 0, k), cvt_lo(c0), a0); \
    a1 = fmaf(RW(j + 1, k), cvt_lo(c1), a1); \
    a2 = fmaf(RW(j + 2, k), cvt_lo(c2), a2); \
    a3 = fmaf(RW(j + 3, k), cvt_lo(c3), a3); \
    a0 = fmaf(RW(j + 4, k), cvt_lo(c4), a0); \
    a1 = fmaf(RW(j + 5, k), cvt_lo(c5), a1); \
    a2 = fmaf(RW(j + 6, k), cvt_lo(c6), a2); \
    a3 = fmaf(RW(j + 7, k), cvt_lo(c7), a3); \
    a0 = fmaf(RW(j + 8, k), cvt_lo(c8), a0); \
    a1 = fmaf(RW(j + 9, k), cvt_lo(c9), a1); \
    a2 = fmaf(RW(j + 10, k), cvt_lo(c10), a2); \
    a3 = fmaf(RW(j + 11, k), cvt_lo(c11), a3); \
    a0 = fmaf(RW(j + 12, k), cvt_lo(c12), a0); \
    a1 = fmaf(RW(j + 13, k), cvt_lo(c13), a1); \
    a2 = fmaf(RW(j + 14, k), cvt_lo(c14), a2); \
    a3 = fmaf(RW(j + 15, k), cvt_lo(c15), a3); \
    tp[(TP0) + 0] = packhi(c0, c1); \
    tp[(TP0) + 1] = packhi(c2, c3); \
    tp[(TP0) + 2] = packhi(c4, c5); \
    tp[(TP0) + 3] = packhi(c6, c7); \
    tp[(TP0) + 4] = packhi(c8, c9); \
    tp[(TP0) + 5] = packhi(c10, c11); \
    tp[(TP0) + 6] = packhi(c12, c13); \
    tp[(TP0) + 7] = packhi(c14, c15); \
} while (0)

#define UCONV8(JOFF, TP0) do { \
    int j = beg + (JOFF); \
    int4 sA = *(const int4*)(srcadj + j); \
    int4 sB = *(const int4*)(srcadj + j + 4); \
    unsigned c0 = cmbI[sA.x + lane]; \
    unsigned c1 = cmbI[sA.y + lane]; \
    unsigned c2 = cmbI[sA.z + lane]; \
    unsigned c3 = cmbI[sA.w + lane]; \
    unsigned c4 = cmbI[sB.x + lane]; \
    unsigned c5 = cmbI[sB.y + lane]; \
    unsigned c6 = cmbI[sB.z + lane]; \
    unsigned c7 = cmbI[sB.w + lane]; \
    a0 = fmaf(RW(j + 0, k), cvt_lo(c0), a0); \
    a1 = fmaf(RW(j + 1, k), cvt_lo(c1), a1); \
    a2 = fmaf(RW(j + 2, k), cvt_lo(c2), a2); \
    a3 = fmaf(RW(j + 3, k), cvt_lo(c3), a3); \
    a0 = fmaf(RW(j + 4, k), cvt_lo(c4), a0); \
    a1 = fmaf(RW(j + 5, k), cvt_lo(c5), a1); \
    a2 = fmaf(RW(j + 6, k), cvt_lo(c6), a2); \
    a3 = fmaf(RW(j + 7, k), cvt_lo(c7), a3); \
    tp[(TP0) + 0] = packhi(c0, c1); \
    tp[(TP0) + 1] = packhi(c2, c3); \
    tp[(TP0) + 2] = packhi(c4, c5); \
    tp[(TP0) + 3] = packhi(c6, c7); \
} while (0)

#define UCONV4(JOFF, TP0) do { \
    int j = beg + (JOFF); \
    int4 sA = *(const int4*)(srcadj + j); \
    unsigned c0 = cmbI[sA.x + lane]; \
    unsigned c1 = cmbI[sA.y + lane]; \
    unsigned c2 = cmbI[sA.z + lane]; \
    unsigned c3 = cmbI[sA.w + lane]; \
    a0 = fmaf(RW(j + 0, k), cvt_lo(c0), a0); \
    a1 = fmaf(RW(j + 1, k), cvt_lo(c1), a1); \
    a2 = fmaf(RW(j + 2, k), cvt_lo(c2), a2); \
    a3 = fmaf(RW(j + 3, k), cvt_lo(c3), a3); \
    tp[(TP0) + 0] = packhi(c0, c1); \
    tp[(TP0) + 1] = packhi(c2, c3); \
} while (0)

// fused gather conv + routing score + S/weight update.
// wave per node; lane = dim, k = lane>>4 = factor.
// nlim: NUM_USER on non-layer-end dispatches (item conv output unused there),
// NN on layer-end. Per-user-slot 32B record {jit,n,1/n,w[4]}; wi scattered
// only when flags&8 (it=0 dispatches).
// flags: 1 = layer end (allemb += acc), 4 = write next ego (items: +tanh T),
// 8 = scatter wi.
__global__ __launch_bounds__(256, 4) void k_conv_score(
        const int* __restrict__ ptr, const int* __restrict__ srcadj,
        int4* __restrict__ rec4, float* __restrict__ wi,
        float* __restrict__ S4f, const unsigned short* __restrict__ egoU,
        const unsigned* __restrict__ cmbI, unsigned short* __restrict__ xnextU,
        unsigned* __restrict__ cmbNext, float* __restrict__ allemb,
        int flags, int last, int nlim) {
    int node = (blockIdx.x * blockDim.x + threadIdx.x) >> 6;
    int lane = threadIdx.x & 63;
    if (node >= nlim) return;
    int beg = __builtin_amdgcn_readfirstlane(ptr[node]);
    int end = __builtin_amdgcn_readfirstlane(ptr[node + 1]);
    int count = end - beg;
    int k = lane >> 4;
    int writeWi = flags & 8;
    float* recf = (float*)rec4;

    float a0 = 0.0f, a1 = 0.0f, a2 = 0.0f, a3 = 0.0f;

    if (node >= NUM_USER) {
        // ---- item side: conv only, 16-deep (runs only on layer-end) ----
        int ptrU = __builtin_amdgcn_readfirstlane(ptr[NUM_USER]);
        const float* wT = wi + (size_t)4 * (beg - ptrU);
        int t = 0;
        for (; t + 16 <= count; t += 16) {
            int4 sA = *(const int4*)(srcadj + beg + t);
            int4 sB = *(const int4*)(srcadj + beg + t + 4);
            int4 sC = *(const int4*)(srcadj + beg + t + 8);
            int4 sD = *(const int4*)(srcadj + beg + t + 12);
            a0 = fmaf(wT[4 * t + k], b2f(egoU[sA.x + lane]), a0);
            a1 = fmaf(wT[4 * t + 4 + k], b2f(egoU[sA.y + lane]), a1);
            a2 = fmaf(wT[4 * t + 8 + k], b2f(egoU[sA.z + lane]), a2);
            a3 = fmaf(wT[4 * t + 12 + k], b2f(egoU[sA.w + lane]), a3);
            a0 = fmaf(wT[4 * t + 16 + k], b2f(egoU[sB.x + lane]), a0);
            a1 = fmaf(wT[4 * t + 20 + k], b2f(egoU[sB.y + lane]), a1);
            a2 = fmaf(wT[4 * t + 24 + k], b2f(egoU[sB.z + lane]), a2);
            a3 = fmaf(wT[4 * t + 28 + k], b2f(egoU[sB.w + lane]), a3);
            a0 = fmaf(wT[4 * t + 32 + k], b2f(egoU[sC.x + lane]), a0);
            a1 = fmaf(wT[4 * t + 36 + k], b2f(egoU[sC.y + lane]), a1);
            a2 = fmaf(wT[4 * t + 40 + k], b2f(egoU[sC.z + lane]), a2);
            a3 = fmaf(wT[4 * t + 44 + k], b2f(egoU[sC.w + lane]), a3);
            a0 = fmaf(wT[4 * t + 48 + k], b2f(egoU[sD.x + lane]), a0);
            a1 = fmaf(wT[4 * t + 52 + k], b2f(egoU[sD.y + lane]), a1);
            a2 = fmaf(wT[4 * t + 56 + k], b2f(egoU[sD.z + lane]), a2);
            a3 = fmaf(wT[4 * t + 60 + k], b2f(egoU[sD.w + lane]), a3);
        }
        if (count & 8) {
            int4 sA = *(const int4*)(srcadj + beg + t);
            int4 sB = *(const int4*)(srcadj + beg + t + 4);
            a0 = fmaf(wT[4 * t + k], b2f(egoU[sA.x + lane]), a0);
            a1 = fmaf(wT[4 * t + 4 + k], b2f(egoU[sA.y + lane]), a1);
            a2 = fmaf(wT[4 * t + 8 + k], b2f(egoU[sA.z + lane]), a2);
            a3 = fmaf(wT[4 * t + 12 + k], b2f(egoU[sA.w + lane]), a3);
            a0 = fmaf(wT[4 * t + 16 + k], b2f(egoU[sB.x + lane]), a0);
            a1 = fmaf(wT[4 * t + 20 + k], b2f(egoU[sB.y + lane]), a1);
            a2 = fmaf(wT[4 * t + 24 + k], b2f(egoU[sB.z + lane]), a2);
            a3 = fmaf(wT[4 * t + 28 + k], b2f(egoU[sB.w + lane]), a3);
            t += 8;
        }
        if (count & 4) {
            int4 sA = *(const int4*)(srcadj + beg + t);
            a0 = fmaf(wT[4 * t + k], b2f(egoU[sA.x + lane]), a0);
            a1 = fmaf(wT[4 * t + 4 + k], b2f(egoU[sA.y + lane]), a1);
            a2 = fmaf(wT[4 * t + 8 + k], b2f(egoU[sA.z + lane]), a2);
            a3 = fmaf(wT[4 * t + 12 + k], b2f(egoU[sA.w + lane]), a3);
        }
        float acc = (a0 + a1) + (a2 + a3);
        if (flags & 1) {
            int i = node * DIM + lane;
            allemb[i] += acc;
            if (flags & 4) {
                float ss = red16(acc * acc);
                float tt = tanhf(acc / fmaxf(sqrtf(ss), 1e-12f));
                cmbNext[i - NUM_USER * DIM] =
                    (((unsigned)f2b(tt)) << 16) | (unsigned)f2b(acc);
            }
        }
        return;
    }

    // ---- user side: conv + routing score + fused S/w update ----
    unsigned tp[22];          // packed T cache: 2 slots/word, static-indexed
    bool big = count > MAXU_SLOTS;   // wave-uniform fallback (statistically never)
    int rem = count & 15;
    int rbase = count & ~15;

    if (!big) {
        if (count >= 16) UCONV16(0, 0);
        if (count >= 32) UCONV16(16, 8);
        if (rem & 8) UCONV8(rbase, 16);
        if (rem & 4) UCONV4(rbase + (rem & 8), 20);
    } else {
        for (int j = beg; j < end; j += 4) {
            int4 s = *(const int4*)(srcadj + j);
            a0 = fmaf(RW(j + 0, k), cvt_lo(cmbI[s.x + lane]), a0);
            a1 = fmaf(RW(j + 1, k), cvt_lo(cmbI[s.y + lane]), a1);
            a2 = fmaf(RW(j + 2, k), cvt_lo(cmbI[s.z + lane]), a2);
            a3 = fmaf(RW(j + 3, k), cvt_lo(cmbI[s.w + lane]), a3);
        }
    }
    float acc = (a0 + a1) + (a2 + a3);

    if (flags & 1) {
        int i = node * DIM + lane;
        allemb[i] += acc;
        if (flags & 4) xnextU[i] = f2b(acc);
    }

    // routing score from register cache + fused per-slot S/weight update
    float ssu = red16(acc * acc);
    float u = acc / fmaxf(sqrtf(ssu), 1e-12f);
    bool b0 = lane & 1;
    bool b1 = lane & 2;
    bool b2 = lane & 4;
    bool b3 = lane & 8;

    if (!big) {
#define USC16(JOFF, TP0) do { \
        int j = beg + (JOFF); \
        float p0 = u * __uint_as_float(tp[(TP0) + 0] << 16); \
        float p1 = u * __uint_as_float(tp[(TP0) + 0] & 0xffff0000u); \
        float p2 = u * __uint_as_float(tp[(TP0) + 1] << 16); \
        float p3 = u * __uint_as_float(tp[(TP0) + 1] & 0xffff0000u); \
        float p4 = u * __uint_as_float(tp[(TP0) + 2] << 16); \
        float p5 = u * __uint_as_float(tp[(TP0) + 2] & 0xffff0000u); \
        float p6 = u * __uint_as_float(tp[(TP0) + 3] << 16); \
        float p7 = u * __uint_as_float(tp[(TP0) + 3] & 0xffff0000u); \
        float p8 = u * __uint_as_float(tp[(TP0) + 4] << 16); \
        float p9 = u * __uint_as_float(tp[(TP0) + 4] & 0xffff0000u); \
        float p10 = u * __uint_as_float(tp[(TP0) + 5] << 16); \
        float p11 = u * __uint_as_float(tp[(TP0) + 5] & 0xffff0000u); \
        float p12 = u * __uint_as_float(tp[(TP0) + 6] << 16); \
        float p13 = u * __uint_as_float(tp[(TP0) + 6] & 0xffff0000u); \
        float p14 = u * __uint_as_float(tp[(TP0) + 7] << 16); \
        float p15 = u * __uint_as_float(tp[(TP0) + 7] & 0xffff0000u); \
        float q0 = mixv(p0, p1, b0, 1); \
        float q1 = mixv(p2, p3, b0, 1); \
        float q2 = mixv(p4, p5, b0, 1); \
        float q3 = mixv(p6, p7, b0, 1); \
        float q4 = mixv(p8, p9, b0, 1); \
        float q5 = mixv(p10, p11, b0, 1); \
        float q6 = mixv(p12, p13, b0, 1); \
        float q7 = mixv(p14, p15, b0, 1); \
        float r0 = mixv(q0, q1, b1, 2); \
        float r1 = mixv(q2, q3, b1, 2); \
        float r2 = mixv(q4, q5, b1, 2); \
        float r3 = mixv(q6, q7, b1, 2); \
        float s0 = mixv(r0, r1, b2, 4); \
        float s1 = mixv(r2, r3, b2, 4); \
        float t0 = mixv(s0, s1, b3, 8); \
        fused_upd(j + (lane & 15), k, t0, true, \
                  rec4, S4f, wi, last, writeWi); \
} while (0)
        if (count >= 16) USC16(0, 0);
        if (count >= 32) USC16(16, 8);
        if (rem & 8) {
            int j = beg + rbase;
            float p0 = u * __uint_as_float(tp[16] << 16);
            float p1 = u * __uint_as_float(tp[16] & 0xffff0000u);
            float p2 = u * __uint_as_float(tp[17] << 16);
            float p3 = u * __uint_as_float(tp[17] & 0xffff0000u);
            float p4 = u * __uint_as_float(tp[18] << 16);
            float p5 = u * __uint_as_float(tp[18] & 0xffff0000u);
            float p6 = u * __uint_as_float(tp[19] << 16);
            float p7 = u * __uint_as_float(tp[19] & 0xffff0000u);
            float q0 = mixv(p0, p1, b0, 1);
            float q1 = mixv(p2, p3, b0, 1);
            float q2 = mixv(p4, p5, b0, 1);
            float q3 = mixv(p6, p7, b0, 1);
            float r0 = mixv(q0, q1, b1, 2);
            float r1 = mixv(q2, q3, b1, 2);
            float t0 = mixv(r0, r1, b2, 4);
            t0 += __shfl_xor(t0, 8);
            fused_upd(j + (lane & 7), k, t0, !(lane & 8),
                      rec4, S4f, wi, last, writeWi);
        }
        if (rem & 4) {
            int j = beg + rbase + (rem & 8);
            float p0 = u * __uint_as_float(tp[20] << 16);
            float p1 = u * __uint_as_float(tp[20] & 0xffff0000u);
            float p2 = u * __uint_as_float(tp[21] << 16);
            float p3 = u * __uint_as_float(tp[21] & 0xffff0000u);
            float q0 = mixv(p0, p1, b0, 1);
            float q1 = mixv(p2, p3, b0, 1);
            float r0 = mixv(q0, q1, b1, 2);
            r0 += __shfl_xor(r0, 4);
            r0 += __shfl_xor(r0, 8);
            fused_upd(j + (lane & 3), k, r0, !(lane & 12),
                      rec4, S4f, wi, last, writeWi);
        }
    } else {
        for (int j = beg; j < end; j += 4) {
            int4 s = *(const int4*)(srcadj + j);
            float p0 = red16(u * cvt_hi(cmbI[s.x + lane]));
            float p1 = red16(u * cvt_hi(cmbI[s.y + lane]));
            float p2 = red16(u * cvt_hi(cmbI[s.z + lane]));
            float p3 = red16(u * cvt_hi(cmbI[s.w + lane]));
            int sl = lane & 3;
            float dv = p0;
            dv = (sl == 1) ? p1 : dv;
            dv = (sl == 2) ? p2 : dv;
            dv = (sl == 3) ? p3 : dv;
            fused_upd(j + sl, k, dv, !(lane & 12),
                      rec4, S4f, wi, last, writeWi);
        }
    }
}

extern "C" void kernel_launch(void* const* d_in, const int* in_sizes, int n_in,
                              void* d_out, int out_size, void* d_ws, size_t ws_size,
                              hipStream_t stream) {
    const float* user = (const float*)d_in[0];
    const float* item = (const float*)d_in[1];
    const float* S_in = (const float*)d_in[2];
    const int* edge = (const int*)d_in[3];
    const int* row0 = edge;
    const int* col0 = edge + NE;

    float* out = (float*)d_out;
    float* allemb = out;              // NN*DIM floats
    float* Sfinal = out + NN * DIM;   // KF*NE floats

    char* ws = (char*)d_ws;
    size_t off = 0;
    auto carve = [&](size_t bytes) { void* p = ws + off; off += (bytes + 255) & ~(size_t)255; return p; };
    int* ptr = (int*)carve((NN + 1) * sizeof(int));
    int* bsum = (int*)carve(256 * sizeof(int));
    int* offs = (int*)carve(256 * sizeof(int));
    int* cnt = (int*)carve((NN + 1) * sizeof(int));       // written by scan1
    int* base8 = (int*)carve((size_t)NPART * NN * sizeof(int));  // written by scan1
    int* srcadj = (int*)carve((size_t)NSLOT_MAX * sizeof(int));
    unsigned* rankR = (unsigned*)carve((size_t)NE * sizeof(int));
    unsigned* rankC = (unsigned*)carve((size_t)NE * sizeof(int));
    int* jpos1 = (int*)carve((size_t)NE * sizeof(int));
    float* dinv = (float*)carve(NN * sizeof(float));
    float4* Scur4 = (float4*)carve((size_t)NEPU_MAX * sizeof(float4));
    // contiguous zero-region: cnt8 | rec (32B/user-slot) | wi  (ONE bulk memset)
    size_t zbeg = off;
    int* cnt8 = (int*)carve((size_t)NPART * NN * sizeof(int));
    int4* rec4 = (int4*)carve((size_t)NEPU_MAX * 2 * sizeof(int4));
    float4* wi = (float4*)carve((size_t)NEPI_MAX * sizeof(float4));
    size_t zlen = off - zbeg;
    unsigned short* egoUA = (unsigned short*)carve((size_t)NUM_USER * DIM * 2);
    unsigned short* egoUB = (unsigned short*)carve((size_t)NUM_USER * DIM * 2);
    unsigned* cmbIA = (unsigned*)carve((size_t)NUM_ITEM * DIM * 4);
    unsigned* cmbIB = (unsigned*)carve((size_t)NUM_ITEM * DIM * 4);

    hipMemsetAsync(ws + zbeg, 0, zlen, stream);

    k_setup<<<NB_SETUP, 256, 0, stream>>>(user, item, egoUA, cmbIA, allemb,
                                          row0, col0, cnt8, rankR, rankC);
    k_scan1<<<NBLK_SCAN, SCAN_CHUNK, 0, stream>>>(cnt8, base8, cnt, dinv, ptr, bsum);
    k_scan2<<<1, 256, 0, stream>>>(bsum, offs);
    k_scan3<<<(NN + 1 + 255) / 256, 256, 0, stream>>>(ptr, offs, cnt, srcadj);
    k_fillw0<<<(NE + 255) / 256, 256, 0, stream>>>(row0, col0, rankR, rankC,
                                                   S_in, dinv, ptr, base8,
                                                   srcadj, rec4, jpos1);

    unsigned short* egoU = egoUA;
    unsigned short* egoUn = egoUB;
    unsigned* cmbI = cmbIA;
    unsigned* cmbIn = cmbIB;
    for (int layer = 0; layer < 2; ++layer) {
        for (int it = 0; it < 2; ++it) {
            int flags = 0;
            if (it == 0) flags |= 8;                   // scatter wi (consumed at it=1)
            if (it == 1) flags |= 1;                   // layer end: allemb += acc
            if (it == 1 && layer == 0) flags |= 4;     // write next ego (+item T)
            int last = (layer == 1 && it == 1) ? 1 : 0;
            // non-layer-end: item x_new is never consumed -> user-only grid
            int nlim = (it == 1) ? NN : NUM_USER;
            k_conv_score<<<(nlim * 64 + 255) / 256, 256, 0, stream>>>(
                ptr, srcadj, rec4, (float*)wi, (float*)Scur4,
                egoU, cmbI, egoUn, cmbIn, allemb, flags, last, nlim);
        }
        unsigned short* t = egoU; egoU = egoUn; egoUn = t;
        unsigned* tc = cmbI; cmbI = cmbIn; cmbIn = tc;
    }
    k_sout<<<(NE / 4 + 255) / 256, 256, 0, stream>>>(Scur4, jpos1, Sfinal);
}

// Round 15
// 351.027 us; speedup vs baseline: 1.0284x; 1.0284x over previous
//
#include <hip/hip_runtime.h>

#define NUM_USER 60000
#define NUM_ITEM 40000
#define NN 100000
#define NE 500000
#define DIM 64
#define KF 4
#define SCAN_CHUNK 512
#define NBLK_SCAN ((NN + 1 + SCAN_CHUNK - 1) / SCAN_CHUNK)
// padded slot-count upper bounds (each node rounds up to multiple of 4)
#define NEPU_MAX (NE + 3 * NUM_USER)   // 680000 user-side slots max
#define NEPI_MAX (NE + 3 * NUM_ITEM)   // 620000 item-side slots max
#define NSLOT_MAX (NEPU_MAX + NEPI_MAX)
#define MAXU_SLOTS 44                  // register-cached user path handles <=44 slots
#define NB_U4 (NUM_USER * DIM / 4 / 256)   // 3750 user-init blocks (float4/thread)
#define NB_I (NUM_ITEM / 16)               // 2500 item-init blocks (16 nodes/block)
#define NB_SETUP (NB_U4 + NB_I)            // 6250
#define EPB (NE / NB_SETUP)                // 80 edges counted per setup block
#define NPART 8                            // count partitions (~XCD count)

// sum within each 16-lane group (butterfly: all lanes get result)
__device__ __forceinline__ float red16(float v) {
    v += __shfl_xor(v, 1);
    v += __shfl_xor(v, 2);
    v += __shfl_xor(v, 4);
    v += __shfl_xor(v, 8);
    return v;
}

__device__ __forceinline__ float b2f(unsigned short u) {
    return __uint_as_float(((unsigned)u) << 16);
}
__device__ __forceinline__ unsigned short f2b(float x) {
    unsigned u = __float_as_uint(x);
    u = (u + 0x7fffu + ((u >> 16) & 1u)) >> 16;   // RNE
    return (unsigned short)u;
}
// combined item word: high16 = T (bf16 bits), low16 = ego (bf16 bits)
__device__ __forceinline__ float cvt_lo(unsigned c) { return __uint_as_float(c << 16); }
__device__ __forceinline__ float cvt_hi(unsigned c) { return __uint_as_float(c & 0xffff0000u); }
// pack hi16 halves of two combined words: lo16(out)=hi16(c0), hi16(out)=hi16(c1)
__device__ __forceinline__ unsigned packhi(unsigned c0, unsigned c1) {
#if defined(__has_builtin) && __has_builtin(__builtin_amdgcn_perm)
    return __builtin_amdgcn_perm(c1, c0, 0x07060302u);
#else
    return (c0 >> 16) | (c1 & 0xffff0000u);
#endif
}
// mixed-butterfly level: lane keeps the value whose slot-bit matches its lane bit
__device__ __forceinline__ float mixv(float x, float y, bool b, int m) {
    return (b ? y : x) + __shfl_xor(b ? x : y, m);
}

__device__ __forceinline__ float4 softmax4(float4 s) {
    float m = fmaxf(fmaxf(s.x, s.y), fmaxf(s.z, s.w));
    float e0 = __expf(s.x - m), e1 = __expf(s.y - m);
    float e2 = __expf(s.z - m), e3 = __expf(s.w - m);
    float inv = 1.0f / (e0 + e1 + e2 + e3);
    return make_float4(e0 * inv, e1 * inv, e2 * inv, e3 * inv);
}

// Per-user-slot 32B record (ONE cache line): rec4[2j]={jit, n, 1/n, 0},
// rec4[2j+1]={w0,w1,w2,w3}. Dummy slots all-zero from bulk memset
// (n=0 -> update skipped; w=0 -> conv contribution zero).
#define RW(j, k) recf[8 * (j) + 4 + (k)]

// Fused per-slot S/weight update (single record: every access to a user slot
// is by its owning lane, read-before-write in program order).
// softmax(S_old) reconstructed as w*(1/n). snew = w*rn + dot.
// last: S4f <- snew (final output); else w' = n*softmax_k(snew) -> record
// (+ wi item-order scatter only when writeWi; it=1's wi is never consumed).
__device__ __forceinline__ void fused_upd(int jj, int k, float dot, bool wr,
        int4* __restrict__ rec4, float* __restrict__ S4f,
        float* __restrict__ wiW, int last, int writeWi) {
    float* recf = (float*)rec4;
    float w = RW(jj, k);
    int4 h = rec4[2 * jj];
    float n = __int_as_float(h.y);
    float rn = __int_as_float(h.z);
    float snew = fmaf(w, rn, dot);
    if (last) {
        if (wr) S4f[4 * jj + k] = snew;
        return;
    }
    float m2 = fmaxf(snew, __shfl_xor(snew, 16));
    m2 = fmaxf(m2, __shfl_xor(m2, 32));
    float e2 = __expf(snew - m2);
    float s2 = e2 + __shfl_xor(e2, 16);
    s2 += __shfl_xor(s2, 32);
    if (wr && n > 0.0f) {
        float wn = n * e2 * (1.0f / s2);
        RW(jj, k) = wn;
        if (writeWi) wiW[4 * h.x + k] = wn;
    }
}

// init (vectorized 4 dims/thread) + PARTITIONED degree count: partition
// p = blockIdx&7 ~ XCD id under round-robin dispatch, so each partition's
// counter lines stay in ONE XCD's L2. Rank packed with p.
__global__ void k_setup(const float* __restrict__ user, const float* __restrict__ item,
                        unsigned short* __restrict__ egoU, unsigned* __restrict__ cmbI,
                        float* __restrict__ allemb, const int* __restrict__ row0,
                        const int* __restrict__ col0, int* __restrict__ cnt8,
                        unsigned* __restrict__ rankR, unsigned* __restrict__ rankC) {
    int b = blockIdx.x, t = threadIdx.x;
    int ebase = b * EPB;
    unsigned ptag = (unsigned)(b & (NPART - 1));
    int* cp = cnt8 + (int)ptag * NN;
    if (t < EPB) {
        int nd = row0[ebase + t];
        rankR[ebase + t] = (unsigned)atomicAdd(&cp[nd], 1) | (ptag << 28);
    } else if (t < 2 * EPB) {
        int nd = col0[ebase + t - EPB];
        rankC[ebase + t - EPB] = (unsigned)atomicAdd(&cp[nd], 1) | (ptag << 28);
    }
    if (b < NB_U4) {
        // user: pure streaming copy, float4/thread
        int idx = (b * 256 + t) * 4;
        float4 v = *(const float4*)(user + idx);
        ushort4 e;
        e.x = f2b(v.x); e.y = f2b(v.y); e.z = f2b(v.z); e.w = f2b(v.w);
        *(ushort4*)(egoU + idx) = e;
        *(float4*)(allemb + idx) = v;
    } else {
        // item: 16 lanes/node, float4/lane; 16-dim norm = 4-lane reduce
        int bb = b - NB_U4;
        int lane = t & 63;
        int nodeI = bb * 16 + ((t >> 6) << 2) + (lane >> 4);
        int idx = nodeI * DIM + (lane & 15) * 4;
        float4 v = *(const float4*)(item + idx);
        float ss = v.x * v.x + v.y * v.y + v.z * v.z + v.w * v.w;
        ss += __shfl_xor(ss, 1);
        ss += __shfl_xor(ss, 2);
        float rinv = 1.0f / fmaxf(sqrtf(ss), 1e-12f);
        uint4 o;
        o.x = (((unsigned)f2b(tanhf(v.x * rinv))) << 16) | (unsigned)f2b(v.x);
        o.y = (((unsigned)f2b(tanhf(v.y * rinv))) << 16) | (unsigned)f2b(v.y);
        o.z = (((unsigned)f2b(tanhf(v.z * rinv))) << 16) | (unsigned)f2b(v.z);
        o.w = (((unsigned)f2b(tanhf(v.w * rinv))) << 16) | (unsigned)f2b(v.w);
        *(uint4*)(cmbI + idx) = o;
        *(float4*)(allemb + NUM_USER * DIM + idx) = v;
    }
}

// --- 3-stage exclusive scan over padded counts -> ptr[NN+1] ---
// scan1 also: sums the 8 count partitions, writes per-partition exclusive
// bases (base8) + total degree (cnt) + dinv.
__global__ void k_scan1(const int* __restrict__ cnt8, int* __restrict__ base8,
                        int* __restrict__ cnt, float* __restrict__ dinv,
                        int* __restrict__ ptr, int* __restrict__ bsum) {
    __shared__ int sm[SCAN_CHUNK];
    int tid = threadIdx.x;
    int idx = blockIdx.x * SCAN_CHUNK + tid;
    int d = 0;
    if (idx < NN) {
#pragma unroll
        for (int p = 0; p < NPART; ++p) {
            base8[p * NN + idx] = d;
            d += cnt8[p * NN + idx];
        }
        cnt[idx] = d;
        dinv[idx] = (d > 0) ? rsqrtf((float)d) : 0.0f;
    }
    int x = (d + 3) & ~3;
    sm[tid] = x;
    __syncthreads();
    for (int off = 1; off < SCAN_CHUNK; off <<= 1) {
        int v = (tid >= off) ? sm[tid - off] : 0;
        __syncthreads();
        sm[tid] += v;
        __syncthreads();
    }
    if (idx <= NN) ptr[idx] = sm[tid] - x;
    if (tid == SCAN_CHUNK - 1) bsum[blockIdx.x] = sm[tid];
}

__global__ void k_scan2(int* __restrict__ bsum, int* __restrict__ offs) {
    __shared__ int sm[256];
    int tid = threadIdx.x;
    int x = (tid < NBLK_SCAN) ? bsum[tid] : 0;
    sm[tid] = x;
    __syncthreads();
    for (int off = 1; off < 256; off <<= 1) {
        int v = (tid >= off) ? sm[tid - off] : 0;
        __syncthreads();
        sm[tid] += v;
        __syncthreads();
    }
    if (tid < NBLK_SCAN) offs[tid] = sm[tid] - x;
}

// finalize scan; MERGE ptr into the partition bases (pbase = ptr + base8,
// one gather instead of two in fillw0); zero dummy-slot srcadj.
__global__ void k_scan3(int* __restrict__ ptr, const int* __restrict__ offs,
                        const int* __restrict__ cnt, int* __restrict__ srcadj,
                        const int* __restrict__ base8, int* __restrict__ pbase) {
    int idx = blockIdx.x * blockDim.x + threadIdx.x;
    if (idx > NN) return;
    int v = ptr[idx] + offs[idx / SCAN_CHUNK];
    ptr[idx] = v;
    if (idx < NN) {
#pragma unroll
        for (int p = 0; p < NPART; ++p)
            pbase[p * NN + idx] = v + base8[p * NN + idx];
        int d = cnt[idx];
        int end = v + ((d + 3) & ~3);
        for (int j = v + d; j < end; ++j) srcadj[j] = 0;
    }
}

// fill CSR + w0, ATOMIC-FREE: j = pbase[p][node] + rank (ONE gather per
// endpoint). Per edge: coalesced row/col/rank/Sin reads, L2/L3-resident
// pbase/dinv gathers, 3 scattered lines: srcadj[j1], srcadj[j0], rec[j1].
__global__ void k_fillw0(const int* __restrict__ row0, const int* __restrict__ col0,
                         const unsigned* __restrict__ rankR,
                         const unsigned* __restrict__ rankC,
                         const float* __restrict__ Sin, const float* __restrict__ dinv,
                         const int* __restrict__ ptr, const int* __restrict__ pbase,
                         int* __restrict__ srcadj, int4* __restrict__ rec4,
                         int* __restrict__ jpos1) {
    int e = blockIdx.x * blockDim.x + threadIdx.x;
    if (e >= NE) return;
    int r = row0[e], c = col0[e];
    int ptrU = ptr[NUM_USER];
    unsigned rr = rankR[e], rc = rankC[e];
    int j1 = pbase[(int)(rr >> 28) * NN + r] + (int)(rr & 0x0FFFFFFFu);
    int j0 = pbase[(int)(rc >> 28) * NN + c] + (int)(rc & 0x0FFFFFFFu);
    srcadj[j1] = (c - NUM_USER) << 6;
    srcadj[j0] = r << 6;
    jpos1[e] = j1;
    float n = dinv[r] * dinv[c];
    float4 s = make_float4(Sin[e], Sin[NE + e], Sin[2 * NE + e], Sin[3 * NE + e]);
    float4 p = softmax4(s);
    rec4[2 * j1] = make_int4(j0 - ptrU, __float_as_int(n),
                             __float_as_int(1.0f / n), 0);
    rec4[2 * j1 + 1] = make_int4(__float_as_int(n * p.x), __float_as_int(n * p.y),
                                 __float_as_int(n * p.z), __float_as_int(n * p.w));
}

// Scur4 (slot order) -> Sout [4][E] edge order; 4 edges/thread
__global__ void k_sout(const float4* __restrict__ Scur4, const int* __restrict__ jpos1,
                       float* __restrict__ Sout) {
    int t4 = blockIdx.x * blockDim.x + threadIdx.x;
    if (t4 >= NE / 4) return;
    int4 jp = ((const int4*)jpos1)[t4];
    float4 s0 = Scur4[jp.x];
    float4 s1 = Scur4[jp.y];
    float4 s2 = Scur4[jp.z];
    float4 s3 = Scur4[jp.w];
    int e = t4 * 4;
    *(float4*)(Sout + e) = make_float4(s0.x, s1.x, s2.x, s3.x);
    *(float4*)(Sout + NE + e) = make_float4(s0.y, s1.y, s2.y, s3.y);
    *(float4*)(Sout + 2 * NE + e) = make_float4(s0.z, s1.z, s2.z, s3.z);
    *(float4*)(Sout + 3 * NE + e) = make_float4(s0.w, s1.w, s2.w, s3.w);
}

// ---- user conv block macros: 16 outstanding gathers per issue point ----
// (srcadj values pre-scaled by DIM; weights from the slot record stream)
#define UCONV16(JOFF, TP0) do { \
    int j = beg + (JOFF); \
    int4 sA = *(const int4*)(srcadj + j); \
    int4 sB = *(const int4*)(srcadj + j + 4); \
    int4 sC = *(const int4*)(srcadj + j + 8); \
    int4 sD = *(const int4*)(srcadj + j + 12); \
    unsigned c0 = cmbI[sA.x + lane]; \
    unsigned c1 = cmbI[sA.y + lane]; \
    unsigned c2 = cmbI[sA.z + lane]; \
    unsigned c3 = cmbI[sA.w + lane]; \
    unsigned c4 = cmbI[sB.x + lane]; \
    unsigned c5 = cmbI[sB.y + lane]; \
    unsigned c6 = cmbI[sB.z + lane]; \
    unsigned c7 = cmbI[sB.w + lane]; \
    unsigned c8 = cmbI[sC.x + lane]; \
    unsigned c9 = cmbI[sC.y + lane]; \
    unsigned c10 = cmbI[sC.z + lane]; \
    unsigned c11 = cmbI[sC.w + lane]; \
    unsigned c12 = cmbI[sD.x + lane]; \
    unsigned c13 = cmbI[sD.y + lane]; \
    unsigned c14 = cmbI[sD.z + lane]; \
    unsigned c15 = cmbI[sD.w + lane]; \
    a0 = fmaf(RW(j + 0, k), cvt_lo(c0), a0); \
    a1 = fmaf(RW(j + 1, k), cvt_lo(c1), a1); \
    a2 = fmaf(RW(j + 2, k), cvt_lo(c2), a2); \
    a3 = fmaf(RW(j + 3, k), cvt_lo(c3), a3); \
    a0 = fmaf(RW(j + 4, k), cvt_lo(c4), a0); \
    a1 = fmaf(RW(j + 5, k), cvt_lo(c5), a1); \
    a2 = fmaf(RW(j + 6, k), cvt_lo(c6), a2); \
    a3 = fmaf(RW(j + 7, k), cvt_lo(c7), a3); \
    a0 = fmaf(RW(j + 8, k), cvt_lo(c8), a0); \
    a1 = fmaf(RW(j + 9, k), cvt_lo(c9), a1); \
    a2 = fmaf(RW(j + 10, k), cvt_lo(c10), a2); \
    a3 = fmaf(RW(j + 11, k), cvt_lo(c11), a3); \
    a0 = fmaf(RW(j + 12, k), cvt_lo(c12), a0); \
    a1 = fmaf(RW(j + 13, k), cvt_lo(c13), a1); \
    a2 = fmaf(RW(j + 14, k), cvt_lo(c14), a2); \
    a3 = fmaf(RW(j + 15, k), cvt_lo(c15), a3); \
    tp[(TP0) + 0] = packhi(c0, c1); \
    tp[(TP0) + 1] = packhi(c2, c3); \
    tp[(TP0) + 2] = packhi(c4, c5); \
    tp[(TP0) + 3] = packhi(c6, c7); \
    tp[(TP0) + 4] = packhi(c8, c9); \
    tp[(TP0) + 5] = packhi(c10, c11); \
    tp[(TP0) + 6] = packhi(c12, c13); \
    tp[(TP0) + 7] = packhi(c14, c15); \
} while (0)

#define UCONV8(JOFF, TP0) do { \
    int j = beg + (JOFF); \
    int4 sA = *(const int4*)(srcadj + j); \
    int4 sB = *(const int4*)(srcadj + j + 4); \
    unsigned c0 = cmbI[sA.x + lane]; \
    unsigned c1 = cmbI[sA.y + lane]; \
    unsigned c2 = cmbI[sA.z + lane]; \
    unsigned c3 = cmbI[sA.w + lane]; \
    unsigned c4 = cmbI[sB.x + lane]; \
    unsigned c5 = cmbI[sB.y + lane]; \
    unsigned c6 = cmbI[sB.z + lane]; \
    unsigned c7 = cmbI[sB.w + lane]; \
    a0 = fmaf(RW(j + 0, k), cvt_lo(c0), a0); \
    a1 = fmaf(RW(j + 1, k), cvt_lo(c1), a1); \
    a2 = fmaf(RW(j + 2, k), cvt_lo(c2), a2); \
    a3 = fmaf(RW(j + 3, k), cvt_lo(c3), a3); \
    a0 = fmaf(RW(j + 4, k), cvt_lo(c4), a0); \
    a1 = fmaf(RW(j + 5, k), cvt_lo(c5), a1); \
    a2 = fmaf(RW(j + 6, k), cvt_lo(c6), a2); \
    a3 = fmaf(RW(j + 7, k), cvt_lo(c7), a3); \
    tp[(TP0) + 0] = packhi(c0, c1); \
    tp[(TP0) + 1] = packhi(c2, c3); \
    tp[(TP0) + 2] = packhi(c4, c5); \
    tp[(TP0) + 3] = packhi(c6, c7); \
} while (0)

#define UCONV4(JOFF, TP0) do { \
    int j = beg + (JOFF); \
    int4 sA = *(const int4*)(srcadj + j); \
    unsigned c0 = cmbI[sA.x + lane]; \
    unsigned c1 = cmbI[sA.y + lane]; \
    unsigned c2 = cmbI[sA.z + lane]; \
    unsigned c3 = cmbI[sA.w + lane]; \
    a0 = fmaf(RW(j + 0, k), cvt_lo(c0), a0); \
    a1 = fmaf(RW(j + 1, k), cvt_lo(c1), a1); \
    a2 = fmaf(RW(j + 2, k), cvt_lo(c2), a2); \
    a3 = fmaf(RW(j + 3, k), cvt_lo(c3), a3); \
    tp[(TP0) + 0] = packhi(c0, c1); \
    tp[(TP0) + 1] = packhi(c2, c3); \
} while (0)

// fused gather conv + routing score + S/weight update.
// wave per node; lane = dim, k = lane>>4 = factor.
// nlim: NUM_USER on non-layer-end dispatches (item conv output unused there),
// NN on layer-end. Per-user-slot 32B record {jit,n,1/n,w[4]}; wi scattered
// only when flags&8 (it=0 dispatches).
// flags: 1 = layer end (allemb += acc), 4 = write next ego (items: +tanh T),
// 8 = scatter wi.
__global__ __launch_bounds__(256, 4) void k_conv_score(
        const int* __restrict__ ptr, const int* __restrict__ srcadj,
        int4* __restrict__ rec4, float* __restrict__ wi,
        float* __restrict__ S4f, const unsigned short* __restrict__ egoU,
        const unsigned* __restrict__ cmbI, unsigned short* __restrict__ xnextU,
        unsigned* __restrict__ cmbNext, float* __restrict__ allemb,
        int flags, int last, int nlim) {
    int node = (blockIdx.x * blockDim.x + threadIdx.x) >> 6;
    int lane = threadIdx.x & 63;
    if (node >= nlim) return;
    int beg = __builtin_amdgcn_readfirstlane(ptr[node]);
    int end = __builtin_amdgcn_readfirstlane(ptr[node + 1]);
    int count = end - beg;
    int k = lane >> 4;
    int writeWi = flags & 8;
    float* recf = (float*)rec4;

    float a0 = 0.0f, a1 = 0.0f, a2 = 0.0f, a3 = 0.0f;

    if (node >= NUM_USER) {
        // ---- item side: conv only, 16-deep (runs only on layer-end) ----
        int ptrU = __builtin_amdgcn_readfirstlane(ptr[NUM_USER]);
        const float* wT = wi + (size_t)4 * (beg - ptrU);
        int t = 0;
        for (; t + 16 <= count; t += 16) {
            int4 sA = *(const int4*)(srcadj + beg + t);
            int4 sB = *(const int4*)(srcadj + beg + t + 4);
            int4 sC = *(const int4*)(srcadj + beg + t + 8);
            int4 sD = *(const int4*)(srcadj + beg + t + 12);
            a0 = fmaf(wT[4 * t + k], b2f(egoU[sA.x + lane]), a0);
            a1 = fmaf(wT[4 * t + 4 + k], b2f(egoU[sA.y + lane]), a1);
            a2 = fmaf(wT[4 * t + 8 + k], b2f(egoU[sA.z + lane]), a2);
            a3 = fmaf(wT[4 * t + 12 + k], b2f(egoU[sA.w + lane]), a3);
            a0 = fmaf(wT[4 * t + 16 + k], b2f(egoU[sB.x + lane]), a0);
            a1 = fmaf(wT[4 * t + 20 + k], b2f(egoU[sB.y + lane]), a1);
            a2 = fmaf(wT[4 * t + 24 + k], b2f(egoU[sB.z + lane]), a2);
            a3 = fmaf(wT[4 * t + 28 + k], b2f(egoU[sB.w + lane]), a3);
            a0 = fmaf(wT[4 * t + 32 + k], b2f(egoU[sC.x + lane]), a0);
            a1 = fmaf(wT[4 * t + 36 + k], b2f(egoU[sC.y + lane]), a1);
            a2 = fmaf(wT[4 * t + 40 + k], b2f(egoU[sC.z + lane]), a2);
            a3 = fmaf(wT[4 * t + 44 + k], b2f(egoU[sC.w + lane]), a3);
            a0 = fmaf(wT[4 * t + 48 + k], b2f(egoU[sD.x + lane]), a0);
            a1 = fmaf(wT[4 * t + 52 + k], b2f(egoU[sD.y + lane]), a1);
            a2 = fmaf(wT[4 * t + 56 + k], b2f(egoU[sD.z + lane]), a2);
            a3 = fmaf(wT[4 * t + 60 + k], b2f(egoU[sD.w + lane]), a3);
        }
        if (count & 8) {
            int4 sA = *(const int4*)(srcadj + beg + t);
            int4 sB = *(const int4*)(srcadj + beg + t + 4);
            a0 = fmaf(wT[4 * t + k], b2f(egoU[sA.x + lane]), a0);
            a1 = fmaf(wT[4 * t + 4 + k], b2f(egoU[sA.y + lane]), a1);
            a2 = fmaf(wT[4 * t + 8 + k], b2f(egoU[sA.z + lane]), a2);
            a3 = fmaf(wT[4 * t + 12 + k], b2f(egoU[sA.w + lane]), a3);
            a0 = fmaf(wT[4 * t + 16 + k], b2f(egoU[sB.x + lane]), a0);
            a1 = fmaf(wT[4 * t + 20 + k], b2f(egoU[sB.y + lane]), a1);
            a2 = fmaf(wT[4 * t + 24 + k], b2f(egoU[sB.z + lane]), a2);
            a3 = fmaf(wT[4 * t + 28 + k], b2f(egoU[sB.w + lane]), a3);
            t += 8;
        }
        if (count & 4) {
            int4 sA = *(const int4*)(srcadj + beg + t);
            a0 = fmaf(wT[4 * t + k], b2f(egoU[sA.x + lane]), a0);
            a1 = fmaf(wT[4 * t + 4 + k], b2f(egoU[sA.y + lane]), a1);
            a2 = fmaf(wT[4 * t + 8 + k], b2f(egoU[sA.z + lane]), a2);
            a3 = fmaf(wT[4 * t + 12 + k], b2f(egoU[sA.w + lane]), a3);
        }
        float acc = (a0 + a1) + (a2 + a3);
        if (flags & 1) {
            int i = node * DIM + lane;
            allemb[i] += acc;
            if (flags & 4) {
                float ss = red16(acc * acc);
                float tt = tanhf(acc / fmaxf(sqrtf(ss), 1e-12f));
                cmbNext[i - NUM_USER * DIM] =
                    (((unsigned)f2b(tt)) << 16) | (unsigned)f2b(acc);
            }
        }
        return;
    }

    // ---- user side: conv + routing score + fused S/w update ----
    unsigned tp[22];          // packed T cache: 2 slots/word, static-indexed
    bool big = count > MAXU_SLOTS;   // wave-uniform fallback (statistically never)
    int rem = count & 15;
    int rbase = count & ~15;

    if (!big) {
        if (count >= 16) UCONV16(0, 0);
        if (count >= 32) UCONV16(16, 8);
        if (rem & 8) UCONV8(rbase, 16);
        if (rem & 4) UCONV4(rbase + (rem & 8), 20);
    } else {
        for (int j = beg; j < end; j += 4) {
            int4 s = *(const int4*)(srcadj + j);
            a0 = fmaf(RW(j + 0, k), cvt_lo(cmbI[s.x + lane]), a0);
            a1 = fmaf(RW(j + 1, k), cvt_lo(cmbI[s.y + lane]), a1);
            a2 = fmaf(RW(j + 2, k), cvt_lo(cmbI[s.z + lane]), a2);
            a3 = fmaf(RW(j + 3, k), cvt_lo(cmbI[s.w + lane]), a3);
        }
    }
    float acc = (a0 + a1) + (a2 + a3);

    if (flags & 1) {
        int i = node * DIM + lane;
        allemb[i] += acc;
        if (flags & 4) xnextU[i] = f2b(acc);
    }

    // routing score from register cache + fused per-slot S/weight update
    float ssu = red16(acc * acc);
    float u = acc / fmaxf(sqrtf(ssu), 1e-12f);
    bool b0 = lane & 1;
    bool b1 = lane & 2;
    bool b2 = lane & 4;
    bool b3 = lane & 8;

    if (!big) {
#define USC16(JOFF, TP0) do { \
        int j = beg + (JOFF); \
        float p0 = u * __uint_as_float(tp[(TP0) + 0] << 16); \
        float p1 = u * __uint_as_float(tp[(TP0) + 0] & 0xffff0000u); \
        float p2 = u * __uint_as_float(tp[(TP0) + 1] << 16); \
        float p3 = u * __uint_as_float(tp[(TP0) + 1] & 0xffff0000u); \
        float p4 = u * __uint_as_float(tp[(TP0) + 2] << 16); \
        float p5 = u * __uint_as_float(tp[(TP0) + 2] & 0xffff0000u); \
        float p6 = u * __uint_as_float(tp[(TP0) + 3] << 16); \
        float p7 = u * __uint_as_float(tp[(TP0) + 3] & 0xffff0000u); \
        float p8 = u * __uint_as_float(tp[(TP0) + 4] << 16); \
        float p9 = u * __uint_as_float(tp[(TP0) + 4] & 0xffff0000u); \
        float p10 = u * __uint_as_float(tp[(TP0) + 5] << 16); \
        float p11 = u * __uint_as_float(tp[(TP0) + 5] & 0xffff0000u); \
        float p12 = u * __uint_as_float(tp[(TP0) + 6] << 16); \
        float p13 = u * __uint_as_float(tp[(TP0) + 6] & 0xffff0000u); \
        float p14 = u * __uint_as_float(tp[(TP0) + 7] << 16); \
        float p15 = u * __uint_as_float(tp[(TP0) + 7] & 0xffff0000u); \
        float q0 = mixv(p0, p1, b0, 1); \
        float q1 = mixv(p2, p3, b0, 1); \
        float q2 = mixv(p4, p5, b0, 1); \
        float q3 = mixv(p6, p7, b0, 1); \
        float q4 = mixv(p8, p9, b0, 1); \
        float q5 = mixv(p10, p11, b0, 1); \
        float q6 = mixv(p12, p13, b0, 1); \
        float q7 = mixv(p14, p15, b0, 1); \
        float r0 = mixv(q0, q1, b1, 2); \
        float r1 = mixv(q2, q3, b1, 2); \
        float r2 = mixv(q4, q5, b1, 2); \
        float r3 = mixv(q6, q7, b1, 2); \
        float s0 = mixv(r0, r1, b2, 4); \
        float s1 = mixv(r2, r3, b2, 4); \
        float t0 = mixv(s0, s1, b3, 8); \
        fused_upd(j + (lane & 15), k, t0, true, \
                  rec4, S4f, wi, last, writeWi); \
} while (0)
        if (count >= 16) USC16(0, 0);
        if (count >= 32) USC16(16, 8);
        if (rem & 8) {
            int j = beg + rbase;
            float p0 = u * __uint_as_float(tp[16] << 16);
            float p1 = u * __uint_as_float(tp[16] & 0xffff0000u);
            float p2 = u * __uint_as_float(tp[17] << 16);
            float p3 = u * __uint_as_float(tp[17] & 0xffff0000u);
            float p4 = u * __uint_as_float(tp[18] << 16);
            float p5 = u * __uint_as_float(tp[18] & 0xffff0000u);
            float p6 = u * __uint_as_float(tp[19] << 16);
            float p7 = u * __uint_as_float(tp[19] & 0xffff0000u);
            float q0 = mixv(p0, p1, b0, 1);
            float q1 = mixv(p2, p3, b0, 1);
            float q2 = mixv(p4, p5, b0, 1);
            float q3 = mixv(p6, p7, b0, 1);
            float r0 = mixv(q0, q1, b1, 2);
            float r1 = mixv(q2, q3, b1, 2);
            float t0 = mixv(r0, r1, b2, 4);
            t0 += __shfl_xor(t0, 8);
            fused_upd(j + (lane & 7), k, t0, !(lane & 8),
                      rec4, S4f, wi, last, writeWi);
        }
        if (rem & 4) {
            int j = beg + rbase + (rem & 8);
            float p0 = u * __uint_as_float(tp[20] << 16);
            float p1 = u * __uint_as_float(tp[20] & 0xffff0000u);
            float p2 = u * __uint_as_float(tp[21] << 16);
            float p3 = u * __uint_as_float(tp[21] & 0xffff0000u);
            float q0 = mixv(p0, p1, b0, 1);
            float q1 = mixv(p2, p3, b0, 1);
            float r0 = mixv(q0, q1, b1, 2);
            r0 += __shfl_xor(r0, 4);
            r0 += __shfl_xor(r0, 8);
            fused_upd(j + (lane & 3), k, r0, !(lane & 12),
                      rec4, S4f, wi, last, writeWi);
        }
    } else {
        for (int j = beg; j < end; j += 4) {
            int4 s = *(const int4*)(srcadj + j);
            float p0 = red16(u * cvt_hi(cmbI[s.x + lane]));
            float p1 = red16(u * cvt_hi(cmbI[s.y + lane]));
            float p2 = red16(u * cvt_hi(cmbI[s.z + lane]));
            float p3 = red16(u * cvt_hi(cmbI[s.w + lane]));
            int sl = lane & 3;
            float dv = p0;
            dv = (sl == 1) ? p1 : dv;
            dv = (sl == 2) ? p2 : dv;
            dv = (sl == 3) ? p3 : dv;
            fused_upd(j + sl, k, dv, !(lane & 12),
                      rec4, S4f, wi, last, writeWi);
        }
    }
}

extern "C" void kernel_launch(void* const* d_in, const int* in_sizes, int n_in,
                              void* d_out, int out_size, void* d_ws, size_t ws_size,
                              hipStream_t stream) {
    const float* user = (const float*)d_in[0];
    const float* item = (const float*)d_in[1];
    const float* S_in = (const float*)d_in[2];
    const int* edge = (const int*)d_in[3];
    const int* row0 = edge;
    const int* col0 = edge + NE;

    float* out = (float*)d_out;
    float* allemb = out;              // NN*DIM floats
    float* Sfinal = out + NN * DIM;   // KF*NE floats

    char* ws = (char*)d_ws;
    size_t off = 0;
    auto carve = [&](size_t bytes) { void* p = ws + off; off += (bytes + 255) & ~(size_t)255; return p; };
    int* ptr = (int*)carve((NN + 1) * sizeof(int));
    int* bsum = (int*)carve(256 * sizeof(int));
    int* offs = (int*)carve(256 * sizeof(int));
    int* cnt = (int*)carve((NN + 1) * sizeof(int));       // written by scan1
    int* base8 = (int*)carve((size_t)NPART * NN * sizeof(int));  // written by scan1
    int* pbase = (int*)carve((size_t)NPART * NN * sizeof(int));  // written by scan3
    int* srcadj = (int*)carve((size_t)NSLOT_MAX * sizeof(int));
    unsigned* rankR = (unsigned*)carve((size_t)NE * sizeof(int));
    unsigned* rankC = (unsigned*)carve((size_t)NE * sizeof(int));
    int* jpos1 = (int*)carve((size_t)NE * sizeof(int));
    float* dinv = (float*)carve(NN * sizeof(float));
    float4* Scur4 = (float4*)carve((size_t)NEPU_MAX * sizeof(float4));
    // contiguous zero-region: cnt8 | rec (32B/user-slot) | wi  (ONE bulk memset)
    size_t zbeg = off;
    int* cnt8 = (int*)carve((size_t)NPART * NN * sizeof(int));
    int4* rec4 = (int4*)carve((size_t)NEPU_MAX * 2 * sizeof(int4));
    float4* wi = (float4*)carve((size_t)NEPI_MAX * sizeof(float4));
    size_t zlen = off - zbeg;
    unsigned short* egoUA = (unsigned short*)carve((size_t)NUM_USER * DIM * 2);
    unsigned short* egoUB = (unsigned short*)carve((size_t)NUM_USER * DIM * 2);
    unsigned* cmbIA = (unsigned*)carve((size_t)NUM_ITEM * DIM * 4);
    unsigned* cmbIB = (unsigned*)carve((size_t)NUM_ITEM * DIM * 4);

    hipMemsetAsync(ws + zbeg, 0, zlen, stream);

    k_setup<<<NB_SETUP, 256, 0, stream>>>(user, item, egoUA, cmbIA, allemb,
                                          row0, col0, cnt8, rankR, rankC);
    k_scan1<<<NBLK_SCAN, SCAN_CHUNK, 0, stream>>>(cnt8, base8, cnt, dinv, ptr, bsum);
    k_scan2<<<1, 256, 0, stream>>>(bsum, offs);
    k_scan3<<<(NN + 1 + 255) / 256, 256, 0, stream>>>(ptr, offs, cnt, srcadj,
                                                      base8, pbase);
    k_fillw0<<<(NE + 255) / 256, 256, 0, stream>>>(row0, col0, rankR, rankC,
                                                   S_in, dinv, ptr, pbase,
                                                   srcadj, rec4, jpos1);

    unsigned short* egoU = egoUA;
    unsigned short* egoUn = egoUB;
    unsigned* cmbI = cmbIA;
    unsigned* cmbIn = cmbIB;
    for (int layer = 0; layer < 2; ++layer) {
        for (int it = 0; it < 2; ++it) {
            int flags = 0;
            if (it == 0) flags |= 8;                   // scatter wi (consumed at it=1)
            if (it == 1) flags |= 1;                   // layer end: allemb += acc
            if (it == 1 && layer == 0) flags |= 4;     // write next ego (+item T)
            int last = (layer == 1 && it == 1) ? 1 : 0;
            // non-layer-end: item x_new is never consumed -> user-only grid
            int nlim = (it == 1) ? NN : NUM_USER;
            k_conv_score<<<(nlim * 64 + 255) / 256, 256, 0, stream>>>(
                ptr, srcadj, rec4, (float*)wi, (float*)Scur4,
                egoU, cmbI, egoUn, cmbIn, allemb, flags, last, nlim);
        }
        unsigned short* t = egoU; egoU = egoUn; egoUn = t;
        unsigned* tc = cmbI; cmbI = cmbIn; cmbIn = tc;
    }
    k_sout<<<(NE / 4 + 255) / 256, 256, 0, stream>>>(Scur4, jpos1, Sfinal);
}